// Round 3
// baseline (2992.688 us; speedup 1.0000x reference)
//
#include <hip/hip_runtime.h>
#include <hip/hip_bf16.h>
#include <math.h>

#define NB   2
#define TLEN 1024
#define NTOK 2048            // NB*TLEN
#define DM   768             // D_MODEL
#define DI   1536            // D_INNER
#define DS   16              // D_STATE
#define NE   8               // N_EXP
#define DFF  3072            // D_FF
#define NPAIR 4096           // NTOK*2

// ---------------- utility ----------------
__device__ __forceinline__ float blockReduceSum256(float v, float* red4) {
  int lane = threadIdx.x & 63, wid = threadIdx.x >> 6;
#pragma unroll
  for (int m = 32; m; m >>= 1) v += __shfl_xor(v, m, 64);
  if (lane == 0) red4[wid] = v;
  __syncthreads();
  return red4[0] + red4[1] + red4[2] + red4[3];
}

__device__ __forceinline__ float siluf(float x) { return x / (1.f + expf(-x)); }

// ---------------- kernels ----------------
__global__ void k_zero(int* p, int n) {
  int i = blockIdx.x * blockDim.x + threadIdx.x;
  if (i < n) p[i] = 0;
}

// RMSNorm with gamma: h = x * rsqrt(mean(x^2)+eps) * g
__global__ __launch_bounds__(256) void k_rms1(const float* __restrict__ x,
                                              const float* __restrict__ g,
                                              float* __restrict__ h) {
  __shared__ float red[4];
  int n = blockIdx.x, tid = threadIdx.x;
  const float* xr = x + (size_t)n * DM;
  float v0 = xr[tid], v1 = xr[tid + 256], v2 = xr[tid + 512];
  float s = v0 * v0 + v1 * v1 + v2 * v2;
  s = blockReduceSum256(s, red);
  float r = rsqrtf(s / (float)DM + 1e-6f);
  float* hr = h + (size_t)n * DM;
  hr[tid]       = v0 * r * g[tid];
  hr[tid + 256] = v1 * r * g[tid + 256];
  hr[tid + 512] = v2 * r * g[tid + 512];
}

// C[M,N] = A[M,K] @ B[K,N] (+ Res). 128x128 tile, 256 thr, 8x8 micro-tile.
// LDS padded to 132 floats leading dim: keeps float4 alignment (132%4==0),
// spreads transposed-A stores to 2-way bank aliasing (free on CDNA4).
__global__ __launch_bounds__(256, 2) void k_gemm128(const float* __restrict__ A,
                                                    const float* __restrict__ B,
                                                    const float* __restrict__ Res,
                                                    float* __restrict__ C,
                                                    int M, int N, int K) {
  __shared__ float As[16][132];
  __shared__ float Bs[16][132];
  int tid = threadIdx.x;
  int bm = blockIdx.y * 128, bn = blockIdx.x * 128;
  int ar = tid >> 2, ak = (tid & 3) << 2;    // A: rows ar, ar+64; k-chunk ak
  int bk = tid >> 5, bq = (tid & 31) << 2;   // B: k rows bk, bk+8; cols bq
  int tx = tid & 15, ty = tid >> 4;
  float acc[2][2][4][4] = {};
  for (int k0 = 0; k0 < K; k0 += 16) {
    float4 av0 = *(const float4*)(A + (size_t)(bm + ar) * K + k0 + ak);
    float4 av1 = *(const float4*)(A + (size_t)(bm + ar + 64) * K + k0 + ak);
    float4 bv0 = *(const float4*)(B + (size_t)(k0 + bk) * N + bn + bq);
    float4 bv1 = *(const float4*)(B + (size_t)(k0 + bk + 8) * N + bn + bq);
    As[ak + 0][ar] = av0.x; As[ak + 1][ar] = av0.y;
    As[ak + 2][ar] = av0.z; As[ak + 3][ar] = av0.w;
    As[ak + 0][ar + 64] = av1.x; As[ak + 1][ar + 64] = av1.y;
    As[ak + 2][ar + 64] = av1.z; As[ak + 3][ar + 64] = av1.w;
    *(float4*)&Bs[bk][bq] = bv0;
    *(float4*)&Bs[bk + 8][bq] = bv1;
    __syncthreads();
#pragma unroll
    for (int k = 0; k < 16; ++k) {
      float4 a0 = *(const float4*)&As[k][ty << 2];
      float4 a1 = *(const float4*)&As[k][(ty << 2) + 64];
      float4 b0 = *(const float4*)&Bs[k][tx << 2];
      float4 b1 = *(const float4*)&Bs[k][(tx << 2) + 64];
      float aa[2][4] = {{a0.x, a0.y, a0.z, a0.w}, {a1.x, a1.y, a1.z, a1.w}};
      float bb[2][4] = {{b0.x, b0.y, b0.z, b0.w}, {b1.x, b1.y, b1.z, b1.w}};
#pragma unroll
      for (int ih = 0; ih < 2; ++ih)
#pragma unroll
        for (int i = 0; i < 4; ++i)
#pragma unroll
          for (int jh = 0; jh < 2; ++jh)
#pragma unroll
            for (int j = 0; j < 4; ++j)
              acc[ih][jh][i][j] += aa[ih][i] * bb[jh][j];
    }
    __syncthreads();
  }
#pragma unroll
  for (int ih = 0; ih < 2; ++ih)
#pragma unroll
    for (int i = 0; i < 4; ++i) {
      int r = bm + (ih << 6) + (ty << 2) + i;
#pragma unroll
      for (int jh = 0; jh < 2; ++jh) {
        size_t ci = (size_t)r * N + bn + (jh << 6) + (tx << 2);
        float4 v = make_float4(acc[ih][jh][i][0], acc[ih][jh][i][1],
                               acc[ih][jh][i][2], acc[ih][jh][i][3]);
        if (Res) {
          float4 rr = *(const float4*)(Res + ci);
          v.x += rr.x; v.y += rr.y; v.z += rr.z; v.w += rr.w;
        }
        *(float4*)(C + ci) = v;
      }
    }
}

// causal depthwise conv (K=4) + silu.  xz row stride 2*DI; x_s = first DI cols.
__global__ __launch_bounds__(256) void k_conv(const float* __restrict__ xz,
                                              const float* __restrict__ cw,
                                              const float* __restrict__ cb,
                                              float* __restrict__ xc) {
  int idx = blockIdx.x * 256 + threadIdx.x;  // < NTOK*DI
  int d = idx % DI, n = idx / DI;
  int t = n & (TLEN - 1);
  float4 w4 = *(const float4*)(cw + (size_t)d * 4);
  float wv[4] = {w4.x, w4.y, w4.z, w4.w};
  float acc = cb[d];
#pragma unroll
  for (int k = 0; k < 4; ++k) {
    int back = 3 - k;
    if (t >= back) acc += xz[(size_t)(n - back) * (2 * DI) + d] * wv[k];
  }
  xc[idx] = siluf(acc);
}

// params[n,0:33] = xc[n,:] @ w_xproj ; one wave per token, lanes 0..32 active
__global__ __launch_bounds__(256) void k_xproj(const float* __restrict__ xc,
                                               const float* __restrict__ wxp,
                                               float* __restrict__ params) {
  int wid = threadIdx.x >> 6, lane = threadIdx.x & 63;
  int n = blockIdx.x * 4 + wid;
  if (lane >= 33) return;
  const float* xr = xc + (size_t)n * DI;
  float acc = 0.f;
#pragma unroll 4
  for (int dd = 0; dd < DI; ++dd) acc += xr[dd] * wxp[(size_t)dd * 33 + lane];
  params[(size_t)n * 33 + lane] = acc;
}

// selective scan: 16 lanes per (b,d) own one state each; shuffle-reduce for y
__global__ __launch_bounds__(256) void k_scan(const float* __restrict__ params,
                                              const float* __restrict__ xc,
                                              const float* __restrict__ xz,
                                              const float* __restrict__ w_dt,
                                              const float* __restrict__ b_dt,
                                              const float* __restrict__ A_log,
                                              const float* __restrict__ D_skip,
                                              float* __restrict__ y) {
  int gid = blockIdx.x * 256 + threadIdx.x;
  int s = gid & 15;
  int scan = gid >> 4;          // 0..3071
  int b = scan / DI, d = scan % DI;
  float Acoef = -expf(A_log[(size_t)d * DS + s]);
  float wdt = w_dt[d], bdt = b_dt[d], Dsk = D_skip[d];
  float hst = 0.f;
  const float* pbase = params + (size_t)b * TLEN * 33;
  const float* xcb = xc + (size_t)b * TLEN * DI + d;
  const float* zb = xz + (size_t)b * TLEN * (2 * DI) + DI + d;
  float* yb = y + (size_t)b * TLEN * DI + d;
  for (int t = 0; t < TLEN; ++t) {
    const float* pr = pbase + (size_t)t * 33;
    float dtv = pr[32] * wdt + bdt;
    dtv = (dtv > 20.f) ? dtv : log1pf(expf(dtv));
    float ab = expf(dtv * Acoef);
    float xcv = xcb[(size_t)t * DI];
    hst = ab * hst + dtv * pr[s] * xcv;
    float p = hst * pr[16 + s];
    p += __shfl_xor(p, 1, 16);
    p += __shfl_xor(p, 2, 16);
    p += __shfl_xor(p, 4, 16);
    p += __shfl_xor(p, 8, 16);
    if (s == 0) {
      float zv = zb[(size_t)t * (2 * DI)];
      yb[(size_t)t * DI] = (p + xcv * Dsk) * (zv / (1.f + expf(-zv)));
    }
  }
}

// router: rms (stored as rmsx), scores via g_moe, top-2 + softmax
__global__ __launch_bounds__(256) void k_router(const float* __restrict__ x2,
                                                const float* __restrict__ g_moe,
                                                const float* __restrict__ w_router,
                                                float* __restrict__ rmsx,
                                                int* __restrict__ eidx,
                                                float* __restrict__ wtok,
                                                int* __restrict__ counts) {
  __shared__ float red[4];
  __shared__ float esc[4][8];
  int n = blockIdx.x, tid = threadIdx.x;
  const float* xr = x2 + (size_t)n * DM;
  float v[3]; float ss = 0.f;
#pragma unroll
  for (int i = 0; i < 3; ++i) { v[i] = xr[tid + i * 256]; ss += v[i] * v[i]; }
  ss = blockReduceSum256(ss, red);
  float r = rsqrtf(ss / (float)DM + 1e-6f);
  float acc[8] = {};
#pragma unroll
  for (int i = 0; i < 3; ++i) {
    int j = tid + i * 256;
    float rv = v[i] * r;
    rmsx[(size_t)n * DM + j] = rv;
    float hg = rv * g_moe[j];
#pragma unroll
    for (int e = 0; e < 8; ++e) acc[e] += hg * w_router[(size_t)j * 8 + e];
  }
  int lane = tid & 63, wid = tid >> 6;
#pragma unroll
  for (int e = 0; e < 8; ++e) {
    float a = acc[e];
#pragma unroll
    for (int m = 32; m; m >>= 1) a += __shfl_xor(a, m, 64);
    if (lane == 0) esc[wid][e] = a;
  }
  __syncthreads();
  if (tid == 0) {
    float sc[8];
#pragma unroll
    for (int e = 0; e < 8; ++e) sc[e] = esc[0][e] + esc[1][e] + esc[2][e] + esc[3][e];
    int b0 = 0; float v0 = sc[0];
    for (int e = 1; e < 8; ++e) if (sc[e] > v0) { v0 = sc[e]; b0 = e; }
    int b1 = -1; float v1 = -3.4e38f;
    for (int e = 0; e < 8; ++e) if (e != b0 && sc[e] > v1) { v1 = sc[e]; b1 = e; }
    float w0 = 1.f / (1.f + expf(v1 - v0));
    eidx[2 * n] = b0; eidx[2 * n + 1] = b1;
    wtok[2 * n] = w0; wtok[2 * n + 1] = 1.f - w0;
    atomicAdd(&counts[b0], 1);
    atomicAdd(&counts[b1], 1);
  }
}

__global__ void k_prefix(const int* __restrict__ counts, int* __restrict__ offsets) {
  if (threadIdx.x == 0) {
    int o = 0;
    for (int e = 0; e < NE; ++e) { offsets[e] = o; o += counts[e]; }
  }
}

__global__ void k_scatter(const int* __restrict__ eidx, const int* __restrict__ offsets,
                          int* __restrict__ cursors, int* __restrict__ pairTok,
                          int* __restrict__ posOf) {
  int n = blockIdx.x * blockDim.x + threadIdx.x;
  if (n >= NTOK) return;
#pragma unroll
  for (int k = 0; k < 2; ++k) {
    int e = eidx[2 * n + k];
    int pos = offsets[e] + atomicAdd(&cursors[e], 1);
    pairTok[pos] = n;
    posOf[2 * n + k] = pos;
  }
}

// grouped FFN stage 1: G[pair,:] = silu(he@w1[e]) * (he@w3[e]), he = rmsx[tok]*g_exp[e]
// 128x64 tile, 8x4 micro-tile x2 accumulators (acc1, acc3)
__global__ __launch_bounds__(256, 2) void k_ffn1(const float* __restrict__ rmsx,
                                                 const float* __restrict__ g_exp,
                                                 const float* __restrict__ w1,
                                                 const float* __restrict__ w3,
                                                 const int* __restrict__ pairTok,
                                                 const int* __restrict__ offsets,
                                                 const int* __restrict__ counts,
                                                 float* __restrict__ G) {
  int e = blockIdx.z;
  int cnt = counts[e];
  int m0 = blockIdx.y * 128;
  if (m0 >= cnt) return;
  int base = offsets[e];
  int bn = blockIdx.x * 64;
  __shared__ float As[16][132];
  __shared__ float B1s[16][68];
  __shared__ float B3s[16][68];
  int tid = threadIdx.x;
  int ar = tid >> 2, ak = (tid & 3) << 2;
  int bk = tid >> 4, bq = (tid & 15) << 2;
  int tx = tid & 15, ty = tid >> 4;
  int r0 = m0 + ar, r1 = m0 + ar + 64;
  const float* arow0 = (r0 < cnt) ? (rmsx + (size_t)pairTok[base + r0] * DM) : nullptr;
  const float* arow1 = (r1 < cnt) ? (rmsx + (size_t)pairTok[base + r1] * DM) : nullptr;
  const float* ge = g_exp + (size_t)e * DM;
  const float* w1e = w1 + (size_t)e * DM * DFF;
  const float* w3e = w3 + (size_t)e * DM * DFF;
  float acc1[2][4][4] = {}, acc3[2][4][4] = {};
  for (int k0 = 0; k0 < DM; k0 += 16) {
    float4 gv = *(const float4*)(ge + k0 + ak);
    float4 av0 = make_float4(0.f, 0.f, 0.f, 0.f), av1 = av0;
    if (arow0) {
      av0 = *(const float4*)(arow0 + k0 + ak);
      av0.x *= gv.x; av0.y *= gv.y; av0.z *= gv.z; av0.w *= gv.w;
    }
    if (arow1) {
      av1 = *(const float4*)(arow1 + k0 + ak);
      av1.x *= gv.x; av1.y *= gv.y; av1.z *= gv.z; av1.w *= gv.w;
    }
    As[ak + 0][ar] = av0.x; As[ak + 1][ar] = av0.y;
    As[ak + 2][ar] = av0.z; As[ak + 3][ar] = av0.w;
    As[ak + 0][ar + 64] = av1.x; As[ak + 1][ar + 64] = av1.y;
    As[ak + 2][ar + 64] = av1.z; As[ak + 3][ar + 64] = av1.w;
    *(float4*)&B1s[bk][bq] = *(const float4*)(w1e + (size_t)(k0 + bk) * DFF + bn + bq);
    *(float4*)&B3s[bk][bq] = *(const float4*)(w3e + (size_t)(k0 + bk) * DFF + bn + bq);
    __syncthreads();
#pragma unroll
    for (int k = 0; k < 16; ++k) {
      float4 a0 = *(const float4*)&As[k][ty << 2];
      float4 a1 = *(const float4*)&As[k][(ty << 2) + 64];
      float4 b1v = *(const float4*)&B1s[k][tx << 2];
      float4 b3v = *(const float4*)&B3s[k][tx << 2];
      float aa[2][4] = {{a0.x, a0.y, a0.z, a0.w}, {a1.x, a1.y, a1.z, a1.w}};
      float u1[4] = {b1v.x, b1v.y, b1v.z, b1v.w};
      float u3[4] = {b3v.x, b3v.y, b3v.z, b3v.w};
#pragma unroll
      for (int ih = 0; ih < 2; ++ih)
#pragma unroll
        for (int i = 0; i < 4; ++i)
#pragma unroll
          for (int j = 0; j < 4; ++j) {
            acc1[ih][i][j] += aa[ih][i] * u1[j];
            acc3[ih][i][j] += aa[ih][i] * u3[j];
          }
    }
    __syncthreads();
  }
#pragma unroll
  for (int ih = 0; ih < 2; ++ih)
#pragma unroll
    for (int i = 0; i < 4; ++i) {
      int rr = m0 + (ih << 6) + (ty << 2) + i;
      if (rr < cnt) {
        float* gout = G + (size_t)(base + rr) * DFF + bn + (tx << 2);
#pragma unroll
        for (int j = 0; j < 4; ++j) {
          float a = acc1[ih][i][j];
          gout[j] = (a / (1.f + expf(-a))) * acc3[ih][i][j];
        }
      }
    }
}

// grouped FFN stage 2: pOut[pair,:] = G[pair,:] @ w2[e].  128x128 tile, 8x8 micro.
__global__ __launch_bounds__(256, 2) void k_ffn2(const float* __restrict__ G,
                                                 const float* __restrict__ w2,
                                                 const int* __restrict__ offsets,
                                                 const int* __restrict__ counts,
                                                 float* __restrict__ pOut) {
  int e = blockIdx.z;
  int cnt = counts[e];
  int m0 = blockIdx.y * 128;
  if (m0 >= cnt) return;
  int base = offsets[e];
  int bn = blockIdx.x * 128;
  __shared__ float As[16][132];
  __shared__ float Bs[16][132];
  int tid = threadIdx.x;
  int ar = tid >> 2, ak = (tid & 3) << 2;
  int bk = tid >> 5, bq = (tid & 31) << 2;
  int tx = tid & 15, ty = tid >> 4;
  int r0 = m0 + ar, r1 = m0 + ar + 64;
  const float* arow0 = (r0 < cnt) ? (G + (size_t)(base + r0) * DFF) : nullptr;
  const float* arow1 = (r1 < cnt) ? (G + (size_t)(base + r1) * DFF) : nullptr;
  const float* w2e = w2 + (size_t)e * DFF * DM;
  float acc[2][2][4][4] = {};
  for (int k0 = 0; k0 < DFF; k0 += 16) {
    float4 av0 = make_float4(0.f, 0.f, 0.f, 0.f), av1 = av0;
    if (arow0) av0 = *(const float4*)(arow0 + k0 + ak);
    if (arow1) av1 = *(const float4*)(arow1 + k0 + ak);
    As[ak + 0][ar] = av0.x; As[ak + 1][ar] = av0.y;
    As[ak + 2][ar] = av0.z; As[ak + 3][ar] = av0.w;
    As[ak + 0][ar + 64] = av1.x; As[ak + 1][ar + 64] = av1.y;
    As[ak + 2][ar + 64] = av1.z; As[ak + 3][ar + 64] = av1.w;
    *(float4*)&Bs[bk][bq] = *(const float4*)(w2e + (size_t)(k0 + bk) * DM + bn + bq);
    *(float4*)&Bs[bk + 8][bq] = *(const float4*)(w2e + (size_t)(k0 + bk + 8) * DM + bn + bq);
    __syncthreads();
#pragma unroll
    for (int k = 0; k < 16; ++k) {
      float4 a0 = *(const float4*)&As[k][ty << 2];
      float4 a1 = *(const float4*)&As[k][(ty << 2) + 64];
      float4 b0 = *(const float4*)&Bs[k][tx << 2];
      float4 b1 = *(const float4*)&Bs[k][(tx << 2) + 64];
      float aa[2][4] = {{a0.x, a0.y, a0.z, a0.w}, {a1.x, a1.y, a1.z, a1.w}};
      float bb[2][4] = {{b0.x, b0.y, b0.z, b0.w}, {b1.x, b1.y, b1.z, b1.w}};
#pragma unroll
      for (int ih = 0; ih < 2; ++ih)
#pragma unroll
        for (int i = 0; i < 4; ++i)
#pragma unroll
          for (int jh = 0; jh < 2; ++jh)
#pragma unroll
            for (int j = 0; j < 4; ++j)
              acc[ih][jh][i][j] += aa[ih][i] * bb[jh][j];
    }
    __syncthreads();
  }
#pragma unroll
  for (int ih = 0; ih < 2; ++ih)
#pragma unroll
    for (int i = 0; i < 4; ++i) {
      int rr = m0 + (ih << 6) + (ty << 2) + i;
      if (rr < cnt) {
#pragma unroll
        for (int jh = 0; jh < 2; ++jh) {
          float* po = pOut + (size_t)(base + rr) * DM + bn + (jh << 6) + (tx << 2);
          float4 v = make_float4(acc[ih][jh][i][0], acc[ih][jh][i][1],
                                 acc[ih][jh][i][2], acc[ih][jh][i][3]);
          *(float4*)po = v;
        }
      }
    }
}

__global__ __launch_bounds__(256) void k_combine(const float* __restrict__ x2,
                                                 const float* __restrict__ pOut,
                                                 const int* __restrict__ posOf,
                                                 const float* __restrict__ wtok,
                                                 float* __restrict__ out) {
  int idx = blockIdx.x * 256 + threadIdx.x;  // < NTOK*DM
  int n = idx / DM, j = idx % DM;
  out[idx] = x2[idx]
           + wtok[2 * n] * pOut[(size_t)posOf[2 * n] * DM + j]
           + wtok[2 * n + 1] * pOut[(size_t)posOf[2 * n + 1] * DM + j];
}

// ---------------- launcher ----------------
extern "C" void kernel_launch(void* const* d_in, const int* in_sizes, int n_in,
                              void* d_out, int out_size, void* d_ws, size_t ws_size,
                              hipStream_t stream) {
  const float* x       = (const float*)d_in[0];
  const float* g_mamba = (const float*)d_in[1];
  const float* w_in    = (const float*)d_in[2];
  const float* conv_w  = (const float*)d_in[3];
  const float* conv_b  = (const float*)d_in[4];
  const float* w_xproj = (const float*)d_in[5];
  const float* w_dt    = (const float*)d_in[6];
  const float* b_dt    = (const float*)d_in[7];
  const float* A_log   = (const float*)d_in[8];
  const float* D_skip  = (const float*)d_in[9];
  const float* w_out   = (const float*)d_in[10];
  const float* g_moe   = (const float*)d_in[11];
  const float* w_router= (const float*)d_in[12];
  const float* g_exp   = (const float*)d_in[13];
  const float* w1      = (const float*)d_in[14];
  const float* w3      = (const float*)d_in[15];
  const float* w2      = (const float*)d_in[16];
  float* out = (float*)d_out;

  float* f = (float*)d_ws;
  size_t o = 0;
  float* hbuf = f + o;  o += (size_t)NTOK * DM;        // reused as rmsx later
  float* xz   = f + o;  o += (size_t)NTOK * 2 * DI;    // xz+xc+ybuf union == G
  float* xc   = f + o;  o += (size_t)NTOK * DI;        // (NPAIR*DFF floats exactly)
  float* ybuf = f + o;  o += (size_t)NTOK * DI;
  float* G    = xz;                                    // alias: 12,582,912 floats
  float* params = f + o; o += (size_t)NTOK * 33;
  float* x2   = f + o;  o += (size_t)NTOK * DM;
  float* rmsx = hbuf;
  float* pOut = f + o;  o += (size_t)NPAIR * DM;
  float* wtok = f + o;  o += NPAIR;
  int* ib      = (int*)(f + o);
  int* counts  = ib;
  int* offsets = ib + 8;
  int* cursors = ib + 16;
  int* eidx    = ib + 24;
  int* posOf   = ib + 24 + NPAIR;
  int* pairTok = ib + 24 + 2 * NPAIR;

  k_zero<<<1, 64, 0, stream>>>(ib, 24);
  k_rms1<<<NTOK, 256, 0, stream>>>(x, g_mamba, hbuf);
  k_gemm128<<<dim3((2 * DI) / 128, NTOK / 128), 256, 0, stream>>>(hbuf, w_in, nullptr, xz, NTOK, 2 * DI, DM);
  k_conv<<<(NTOK * DI) / 256, 256, 0, stream>>>(xz, conv_w, conv_b, xc);
  k_xproj<<<NTOK / 4, 256, 0, stream>>>(xc, w_xproj, params);
  k_scan<<<(NB * DI * DS) / 256, 256, 0, stream>>>(params, xc, xz, w_dt, b_dt, A_log, D_skip, ybuf);
  k_gemm128<<<dim3(DM / 128, NTOK / 128), 256, 0, stream>>>(ybuf, w_out, x, x2, NTOK, DM, DI);
  k_router<<<NTOK, 256, 0, stream>>>(x2, g_moe, w_router, rmsx, eidx, wtok, counts);
  k_prefix<<<1, 1, 0, stream>>>(counts, offsets);
  k_scatter<<<8, 256, 0, stream>>>(eidx, offsets, cursors, pairTok, posOf);
  k_ffn1<<<dim3(DFF / 64, 16, NE), 256, 0, stream>>>(rmsx, g_exp, w1, w3, pairTok, offsets, counts, G);
  k_ffn2<<<dim3(DM / 128, 16, NE), 256, 0, stream>>>(G, w2, offsets, counts, pOut);
  k_combine<<<(NTOK * DM) / 256, 256, 0, stream>>>(x2, pOut, posOf, wtok, out);
}

// Round 6
// 1897.472 us; speedup vs baseline: 1.5772x; 1.5772x over previous
//
#include <hip/hip_runtime.h>
#include <hip/hip_bf16.h>
#include <math.h>

#define NB   2
#define TLEN 1024
#define NTOK 2048            // NB*TLEN
#define DM   768             // D_MODEL
#define DI   1536            // D_INNER
#define DS   16              // D_STATE
#define NE   8               // N_EXP
#define DFF  3072            // D_FF
#define NPAIR 4096           // NTOK*2
#define NSCAN 3072           // NB*DI
#define CH   32              // scan chunks
#define CL   32              // chunk length (CH*CL == TLEN)

// ---------------- utility ----------------
__device__ __forceinline__ float blockReduceSum256(float v, float* red4) {
  int lane = threadIdx.x & 63, wid = threadIdx.x >> 6;
#pragma unroll
  for (int m = 32; m; m >>= 1) v += __shfl_xor(v, m, 64);
  if (lane == 0) red4[wid] = v;
  __syncthreads();
  return red4[0] + red4[1] + red4[2] + red4[3];
}

__device__ __forceinline__ float siluf(float x) { return x / (1.f + expf(-x)); }

// ---------------- kernels ----------------
__global__ void k_zero(int* p, int n) {
  int i = blockIdx.x * blockDim.x + threadIdx.x;
  if (i < n) p[i] = 0;
}

// RMSNorm with gamma: h = x * rsqrt(mean(x^2)+eps) * g
__global__ __launch_bounds__(256) void k_rms1(const float* __restrict__ x,
                                              const float* __restrict__ g,
                                              float* __restrict__ h) {
  __shared__ float red[4];
  int n = blockIdx.x, tid = threadIdx.x;
  const float* xr = x + (size_t)n * DM;
  float v0 = xr[tid], v1 = xr[tid + 256], v2 = xr[tid + 512];
  float s = v0 * v0 + v1 * v1 + v2 * v2;
  s = blockReduceSum256(s, red);
  float r = rsqrtf(s / (float)DM + 1e-6f);
  float* hr = h + (size_t)n * DM;
  hr[tid]       = v0 * r * g[tid];
  hr[tid + 256] = v1 * r * g[tid + 256];
  hr[tid + 512] = v2 * r * g[tid + 512];
}

// C[M,N] = A[M,K] @ B[K,N] (+ Res). 128x128 tile, 256 thr, 8x8 micro-tile.
__global__ __launch_bounds__(256, 2) void k_gemm128(const float* __restrict__ A,
                                                    const float* __restrict__ B,
                                                    const float* __restrict__ Res,
                                                    float* __restrict__ C,
                                                    int M, int N, int K) {
  __shared__ float As[16][132];
  __shared__ float Bs[16][132];
  int tid = threadIdx.x;
  int bm = blockIdx.y * 128, bn = blockIdx.x * 128;
  int ar = tid >> 2, ak = (tid & 3) << 2;
  int bk = tid >> 5, bq = (tid & 31) << 2;
  int tx = tid & 15, ty = tid >> 4;
  float acc[2][2][4][4] = {};
  for (int k0 = 0; k0 < K; k0 += 16) {
    float4 av0 = *(const float4*)(A + (size_t)(bm + ar) * K + k0 + ak);
    float4 av1 = *(const float4*)(A + (size_t)(bm + ar + 64) * K + k0 + ak);
    float4 bv0 = *(const float4*)(B + (size_t)(k0 + bk) * N + bn + bq);
    float4 bv1 = *(const float4*)(B + (size_t)(k0 + bk + 8) * N + bn + bq);
    As[ak + 0][ar] = av0.x; As[ak + 1][ar] = av0.y;
    As[ak + 2][ar] = av0.z; As[ak + 3][ar] = av0.w;
    As[ak + 0][ar + 64] = av1.x; As[ak + 1][ar + 64] = av1.y;
    As[ak + 2][ar + 64] = av1.z; As[ak + 3][ar + 64] = av1.w;
    *(float4*)&Bs[bk][bq] = bv0;
    *(float4*)&Bs[bk + 8][bq] = bv1;
    __syncthreads();
#pragma unroll
    for (int k = 0; k < 16; ++k) {
      float4 a0 = *(const float4*)&As[k][ty << 2];
      float4 a1 = *(const float4*)&As[k][(ty << 2) + 64];
      float4 b0 = *(const float4*)&Bs[k][tx << 2];
      float4 b1 = *(const float4*)&Bs[k][(tx << 2) + 64];
      float aa[2][4] = {{a0.x, a0.y, a0.z, a0.w}, {a1.x, a1.y, a1.z, a1.w}};
      float bb[2][4] = {{b0.x, b0.y, b0.z, b0.w}, {b1.x, b1.y, b1.z, b1.w}};
#pragma unroll
      for (int ih = 0; ih < 2; ++ih)
#pragma unroll
        for (int i = 0; i < 4; ++i)
#pragma unroll
          for (int jh = 0; jh < 2; ++jh)
#pragma unroll
            for (int j = 0; j < 4; ++j)
              acc[ih][jh][i][j] += aa[ih][i] * bb[jh][j];
    }
    __syncthreads();
  }
#pragma unroll
  for (int ih = 0; ih < 2; ++ih)
#pragma unroll
    for (int i = 0; i < 4; ++i) {
      int r = bm + (ih << 6) + (ty << 2) + i;
#pragma unroll
      for (int jh = 0; jh < 2; ++jh) {
        size_t ci = (size_t)r * N + bn + (jh << 6) + (tx << 2);
        float4 v = make_float4(acc[ih][jh][i][0], acc[ih][jh][i][1],
                               acc[ih][jh][i][2], acc[ih][jh][i][3]);
        if (Res) {
          float4 rr = *(const float4*)(Res + ci);
          v.x += rr.x; v.y += rr.y; v.z += rr.z; v.w += rr.w;
        }
        *(float4*)(C + ci) = v;
      }
    }
}

// causal depthwise conv (K=4) + silu.
__global__ __launch_bounds__(256) void k_conv(const float* __restrict__ xz,
                                              const float* __restrict__ cw,
                                              const float* __restrict__ cb,
                                              float* __restrict__ xc) {
  int idx = blockIdx.x * 256 + threadIdx.x;  // < NTOK*DI
  int d = idx % DI, n = idx / DI;
  int t = n & (TLEN - 1);
  float4 w4 = *(const float4*)(cw + (size_t)d * 4);
  float wv[4] = {w4.x, w4.y, w4.z, w4.w};
  float acc = cb[d];
#pragma unroll
  for (int k = 0; k < 4; ++k) {
    int back = 3 - k;
    if (t >= back) acc += xz[(size_t)(n - back) * (2 * DI) + d] * wv[k];
  }
  xc[idx] = siluf(acc);
}

// transpose w_xproj [1536][33] -> wxpT [33][1536]
__global__ void k_wxpT(const float* __restrict__ wxp, float* __restrict__ wxpT) {
  int idx = blockIdx.x * 256 + threadIdx.x;
  if (idx >= 33 * DI) return;
  int j = idx / DI, dd = idx - j * DI;
  wxpT[idx] = wxp[(size_t)dd * 33 + j];
}

// params[n,0:33] = xc[n,:] @ w_xproj; one block per token, LDS-staged row.
__global__ __launch_bounds__(256) void k_xproj2(const float* __restrict__ xc,
                                                const float* __restrict__ wxpT,
                                                float* __restrict__ params) {
  __shared__ float row[DI];
  __shared__ float psum[132];
  int n = blockIdx.x, tid = threadIdx.x;
  const float* xr = xc + (size_t)n * DI;
#pragma unroll
  for (int i = 0; i < 2; ++i) {
    int q = tid + i * 256;
    if (q < 384) *(float4*)&row[q * 4] = *(const float4*)(xr + q * 4);
  }
  __syncthreads();
  if (tid < 132) {
    int j = tid >> 2, part = tid & 3;
    const float* wr = wxpT + (size_t)j * DI + part * 384;
    const float* rr = row + part * 384;
    float acc = 0.f;
#pragma unroll 4
    for (int q = 0; q < 96; ++q) {
      float4 w4 = *(const float4*)(wr + q * 4);
      float4 r4 = *(const float4*)(rr + q * 4);
      acc += w4.x * r4.x + w4.y * r4.y + w4.z * r4.z + w4.w * r4.w;
    }
    psum[tid] = acc;
  }
  __syncthreads();
  if (tid < 33)
    params[(size_t)n * 33 + tid] =
        psum[tid * 4] + psum[tid * 4 + 1] + psum[tid * 4 + 2] + psum[tid * 4 + 3];
}

// dt[n*DI+d] = softplus(params[n,32]*w_dt[d] + b_dt[d])
__global__ __launch_bounds__(256) void k_dt(const float* __restrict__ params,
                                            const float* __restrict__ w_dt,
                                            const float* __restrict__ b_dt,
                                            float* __restrict__ dtb) {
  int idx = blockIdx.x * 256 + threadIdx.x;  // < NTOK*DI
  int d = idx % DI, n = idx / DI;
  float v = params[(size_t)n * 33 + 32] * w_dt[d] + b_dt[d];
  dtb[idx] = (v > 20.f) ? v : log1pf(expf(v));
}

// scan pass A: per-chunk local scan from 0 -> P (prod of a), S (local state)
__global__ __launch_bounds__(256) void k_scanA(const float* __restrict__ params,
                                               const float* __restrict__ dtb,
                                               const float* __restrict__ xc,
                                               const float* __restrict__ A_log,
                                               float* __restrict__ P,
                                               float* __restrict__ S) {
  int gid = blockIdx.x * 256 + threadIdx.x;   // < CH*NSCAN*DS
  int s = gid & 15;
  int rest = gid >> 4;                        // c*NSCAN + scan
  int scan = rest % NSCAN, c = rest / NSCAN;
  int b = scan / DI, d = scan - b * DI;
  float Acoef = -expf(A_log[(size_t)d * DS + s]);
  float p = 1.f, sl = 0.f;
  int n0 = b * TLEN + c * CL;
#pragma unroll 4
  for (int tt = 0; tt < CL; ++tt) {
    int n = n0 + tt;
    float Bc = params[(size_t)n * 33 + s];
    float dtv = dtb[(size_t)n * DI + d];
    float xcv = xc[(size_t)n * DI + d];
    float a = expf(dtv * Acoef);
    p *= a;
    sl = a * sl + dtv * Bc * xcv;
  }
  P[gid] = p;
  S[gid] = sl;
}

// scan pass B: combine chunk summaries -> Hin[c] (state entering chunk c)
__global__ __launch_bounds__(256) void k_scanB(const float* __restrict__ P,
                                               const float* __restrict__ S,
                                               float* __restrict__ Hin) {
  int j = blockIdx.x * 256 + threadIdx.x;     // < NSCAN*DS
  float H = 0.f;
  for (int c = 0; c < CH; ++c) {
    size_t q = (size_t)c * (NSCAN * DS) + j;
    Hin[q] = H;
    H = P[q] * H + S[q];
  }
}

// scan pass C: replay chunk from Hin, emit y
__global__ __launch_bounds__(256) void k_scanC(const float* __restrict__ params,
                                               const float* __restrict__ dtb,
                                               const float* __restrict__ xc,
                                               const float* __restrict__ xz,
                                               const float* __restrict__ A_log,
                                               const float* __restrict__ D_skip,
                                               const float* __restrict__ Hin,
                                               float* __restrict__ y) {
  int gid = blockIdx.x * 256 + threadIdx.x;   // < CH*NSCAN*DS
  int s = gid & 15;
  int rest = gid >> 4;
  int scan = rest % NSCAN, c = rest / NSCAN;
  int b = scan / DI, d = scan - b * DI;
  float Acoef = -expf(A_log[(size_t)d * DS + s]);
  float Dsk = D_skip[d];
  float hst = Hin[gid];
  int n0 = b * TLEN + c * CL;
  for (int tt = 0; tt < CL; ++tt) {
    int n = n0 + tt;
    const float* pr = params + (size_t)n * 33;
    float Bc = pr[s], Cc = pr[16 + s];
    float dtv = dtb[(size_t)n * DI + d];
    float xcv = xc[(size_t)n * DI + d];
    float a = expf(dtv * Acoef);
    hst = a * hst + dtv * Bc * xcv;
    float p = hst * Cc;
    p += __shfl_xor(p, 1, 16);
    p += __shfl_xor(p, 2, 16);
    p += __shfl_xor(p, 4, 16);
    p += __shfl_xor(p, 8, 16);
    if (s == 0) {
      float zv = xz[(size_t)n * (2 * DI) + DI + d];
      y[(size_t)n * DI + d] = (p + xcv * Dsk) * (zv / (1.f + expf(-zv)));
    }
  }
}

// router: rms (stored as rmsx), scores via g_moe, top-2 + softmax
__global__ __launch_bounds__(256) void k_router(const float* __restrict__ x2,
                                                const float* __restrict__ g_moe,
                                                const float* __restrict__ w_router,
                                                float* __restrict__ rmsx,
                                                int* __restrict__ eidx,
                                                float* __restrict__ wtok,
                                                int* __restrict__ counts) {
  __shared__ float red[4];
  __shared__ float esc[4][8];
  int n = blockIdx.x, tid = threadIdx.x;
  const float* xr = x2 + (size_t)n * DM;
  float v[3]; float ss = 0.f;
#pragma unroll
  for (int i = 0; i < 3; ++i) { v[i] = xr[tid + i * 256]; ss += v[i] * v[i]; }
  ss = blockReduceSum256(ss, red);
  float r = rsqrtf(ss / (float)DM + 1e-6f);
  float acc[8] = {};
#pragma unroll
  for (int i = 0; i < 3; ++i) {
    int j = tid + i * 256;
    float rv = v[i] * r;
    rmsx[(size_t)n * DM + j] = rv;
    float hg = rv * g_moe[j];
#pragma unroll
    for (int e = 0; e < 8; ++e) acc[e] += hg * w_router[(size_t)j * 8 + e];
  }
  int lane = tid & 63, wid = tid >> 6;
#pragma unroll
  for (int e = 0; e < 8; ++e) {
    float a = acc[e];
#pragma unroll
    for (int m = 32; m; m >>= 1) a += __shfl_xor(a, m, 64);
    if (lane == 0) esc[wid][e] = a;
  }
  __syncthreads();
  if (tid == 0) {
    float sc[8];
#pragma unroll
    for (int e = 0; e < 8; ++e) sc[e] = esc[0][e] + esc[1][e] + esc[2][e] + esc[3][e];
    int b0 = 0; float v0 = sc[0];
    for (int e = 1; e < 8; ++e) if (sc[e] > v0) { v0 = sc[e]; b0 = e; }
    int b1 = -1; float v1 = -3.4e38f;
    for (int e = 0; e < 8; ++e) if (e != b0 && sc[e] > v1) { v1 = sc[e]; b1 = e; }
    float w0 = 1.f / (1.f + expf(v1 - v0));
    eidx[2 * n] = b0; eidx[2 * n + 1] = b1;
    wtok[2 * n] = w0; wtok[2 * n + 1] = 1.f - w0;
    atomicAdd(&counts[b0], 1);
    atomicAdd(&counts[b1], 1);
  }
}

__global__ void k_prefix(const int* __restrict__ counts, int* __restrict__ offsets) {
  if (threadIdx.x == 0) {
    int o = 0;
    for (int e = 0; e < NE; ++e) { offsets[e] = o; o += counts[e]; }
  }
}

__global__ void k_scatter(const int* __restrict__ eidx, const int* __restrict__ offsets,
                          int* __restrict__ cursors, int* __restrict__ pairTok,
                          int* __restrict__ posOf) {
  int n = blockIdx.x * blockDim.x + threadIdx.x;
  if (n >= NTOK) return;
#pragma unroll
  for (int k = 0; k < 2; ++k) {
    int e = eidx[2 * n + k];
    int pos = offsets[e] + atomicAdd(&cursors[e], 1);
    pairTok[pos] = n;
    posOf[2 * n + k] = pos;
  }
}

// grouped FFN stage 1: G[pair,:] = silu(he@w1[e]) * (he@w3[e])
__global__ __launch_bounds__(256, 2) void k_ffn1(const float* __restrict__ rmsx,
                                                 const float* __restrict__ g_exp,
                                                 const float* __restrict__ w1,
                                                 const float* __restrict__ w3,
                                                 const int* __restrict__ pairTok,
                                                 const int* __restrict__ offsets,
                                                 const int* __restrict__ counts,
                                                 float* __restrict__ G) {
  int e = blockIdx.z;
  int cnt = counts[e];
  int m0 = blockIdx.y * 128;
  if (m0 >= cnt) return;
  int base = offsets[e];
  int bn = blockIdx.x * 64;
  __shared__ float As[16][132];
  __shared__ float B1s[16][68];
  __shared__ float B3s[16][68];
  int tid = threadIdx.x;
  int ar = tid >> 2, ak = (tid & 3) << 2;
  int bk = tid >> 4, bq = (tid & 15) << 2;
  int tx = tid & 15, ty = tid >> 4;
  int r0 = m0 + ar, r1 = m0 + ar + 64;
  const float* arow0 = (r0 < cnt) ? (rmsx + (size_t)pairTok[base + r0] * DM) : nullptr;
  const float* arow1 = (r1 < cnt) ? (rmsx + (size_t)pairTok[base + r1] * DM) : nullptr;
  const float* ge = g_exp + (size_t)e * DM;
  const float* w1e = w1 + (size_t)e * DM * DFF;
  const float* w3e = w3 + (size_t)e * DM * DFF;
  float acc1[2][4][4] = {}, acc3[2][4][4] = {};
  for (int k0 = 0; k0 < DM; k0 += 16) {
    float4 gv = *(const float4*)(ge + k0 + ak);
    float4 av0 = make_float4(0.f, 0.f, 0.f, 0.f), av1 = av0;
    if (arow0) {
      av0 = *(const float4*)(arow0 + k0 + ak);
      av0.x *= gv.x; av0.y *= gv.y; av0.z *= gv.z; av0.w *= gv.w;
    }
    if (arow1) {
      av1 = *(const float4*)(arow1 + k0 + ak);
      av1.x *= gv.x; av1.y *= gv.y; av1.z *= gv.z; av1.w *= gv.w;
    }
    As[ak + 0][ar] = av0.x; As[ak + 1][ar] = av0.y;
    As[ak + 2][ar] = av0.z; As[ak + 3][ar] = av0.w;
    As[ak + 0][ar + 64] = av1.x; As[ak + 1][ar + 64] = av1.y;
    As[ak + 2][ar + 64] = av1.z; As[ak + 3][ar + 64] = av1.w;
    *(float4*)&B1s[bk][bq] = *(const float4*)(w1e + (size_t)(k0 + bk) * DFF + bn + bq);
    *(float4*)&B3s[bk][bq] = *(const float4*)(w3e + (size_t)(k0 + bk) * DFF + bn + bq);
    __syncthreads();
#pragma unroll
    for (int k = 0; k < 16; ++k) {
      float4 a0 = *(const float4*)&As[k][ty << 2];
      float4 a1 = *(const float4*)&As[k][(ty << 2) + 64];
      float4 b1v = *(const float4*)&B1s[k][tx << 2];
      float4 b3v = *(const float4*)&B3s[k][tx << 2];
      float aa[2][4] = {{a0.x, a0.y, a0.z, a0.w}, {a1.x, a1.y, a1.z, a1.w}};
      float u1[4] = {b1v.x, b1v.y, b1v.z, b1v.w};
      float u3[4] = {b3v.x, b3v.y, b3v.z, b3v.w};
#pragma unroll
      for (int ih = 0; ih < 2; ++ih)
#pragma unroll
        for (int i = 0; i < 4; ++i)
#pragma unroll
          for (int j = 0; j < 4; ++j) {
            acc1[ih][i][j] += aa[ih][i] * u1[j];
            acc3[ih][i][j] += aa[ih][i] * u3[j];
          }
    }
    __syncthreads();
  }
#pragma unroll
  for (int ih = 0; ih < 2; ++ih)
#pragma unroll
    for (int i = 0; i < 4; ++i) {
      int rr = m0 + (ih << 6) + (ty << 2) + i;
      if (rr < cnt) {
        float* gout = G + (size_t)(base + rr) * DFF + bn + (tx << 2);
#pragma unroll
        for (int j = 0; j < 4; ++j) {
          float a = acc1[ih][i][j];
          gout[j] = (a / (1.f + expf(-a))) * acc3[ih][i][j];
        }
      }
    }
}

// grouped FFN stage 2: pOut[pair,:] = G[pair,:] @ w2[e]
__global__ __launch_bounds__(256, 2) void k_ffn2(const float* __restrict__ G,
                                                 const float* __restrict__ w2,
                                                 const int* __restrict__ offsets,
                                                 const int* __restrict__ counts,
                                                 float* __restrict__ pOut) {
  int e = blockIdx.z;
  int cnt = counts[e];
  int m0 = blockIdx.y * 128;
  if (m0 >= cnt) return;
  int base = offsets[e];
  int bn = blockIdx.x * 128;
  __shared__ float As[16][132];
  __shared__ float Bs[16][132];
  int tid = threadIdx.x;
  int ar = tid >> 2, ak = (tid & 3) << 2;
  int bk = tid >> 5, bq = (tid & 31) << 2;
  int tx = tid & 15, ty = tid >> 4;
  int r0 = m0 + ar, r1 = m0 + ar + 64;
  const float* arow0 = (r0 < cnt) ? (G + (size_t)(base + r0) * DFF) : nullptr;
  const float* arow1 = (r1 < cnt) ? (G + (size_t)(base + r1) * DFF) : nullptr;
  const float* w2e = w2 + (size_t)e * DFF * DM;
  float acc[2][2][4][4] = {};
  for (int k0 = 0; k0 < DFF; k0 += 16) {
    float4 av0 = make_float4(0.f, 0.f, 0.f, 0.f), av1 = av0;
    if (arow0) av0 = *(const float4*)(arow0 + k0 + ak);
    if (arow1) av1 = *(const float4*)(arow1 + k0 + ak);
    As[ak + 0][ar] = av0.x; As[ak + 1][ar] = av0.y;
    As[ak + 2][ar] = av0.z; As[ak + 3][ar] = av0.w;
    As[ak + 0][ar + 64] = av1.x; As[ak + 1][ar + 64] = av1.y;
    As[ak + 2][ar + 64] = av1.z; As[ak + 3][ar + 64] = av1.w;
    *(float4*)&Bs[bk][bq] = *(const float4*)(w2e + (size_t)(k0 + bk) * DM + bn + bq);
    *(float4*)&Bs[bk + 8][bq] = *(const float4*)(w2e + (size_t)(k0 + bk + 8) * DM + bn + bq);
    __syncthreads();
#pragma unroll
    for (int k = 0; k < 16; ++k) {
      float4 a0 = *(const float4*)&As[k][ty << 2];
      float4 a1 = *(const float4*)&As[k][(ty << 2) + 64];
      float4 b0 = *(const float4*)&Bs[k][tx << 2];
      float4 b1 = *(const float4*)&Bs[k][(tx << 2) + 64];
      float aa[2][4] = {{a0.x, a0.y, a0.z, a0.w}, {a1.x, a1.y, a1.z, a1.w}};
      float bb[2][4] = {{b0.x, b0.y, b0.z, b0.w}, {b1.x, b1.y, b1.z, b1.w}};
#pragma unroll
      for (int ih = 0; ih < 2; ++ih)
#pragma unroll
        for (int i = 0; i < 4; ++i)
#pragma unroll
          for (int jh = 0; jh < 2; ++jh)
#pragma unroll
            for (int j = 0; j < 4; ++j)
              acc[ih][jh][i][j] += aa[ih][i] * bb[jh][j];
    }
    __syncthreads();
  }
#pragma unroll
  for (int ih = 0; ih < 2; ++ih)
#pragma unroll
    for (int i = 0; i < 4; ++i) {
      int rr = m0 + (ih << 6) + (ty << 2) + i;
      if (rr < cnt) {
#pragma unroll
        for (int jh = 0; jh < 2; ++jh) {
          float* po = pOut + (size_t)(base + rr) * DM + bn + (jh << 6) + (tx << 2);
          float4 v = make_float4(acc[ih][jh][i][0], acc[ih][jh][i][1],
                                 acc[ih][jh][i][2], acc[ih][jh][i][3]);
          *(float4*)po = v;
        }
      }
    }
}

__global__ __launch_bounds__(256) void k_combine(const float* __restrict__ x2,
                                                 const float* __restrict__ pOut,
                                                 const int* __restrict__ posOf,
                                                 const float* __restrict__ wtok,
                                                 float* __restrict__ out) {
  int idx = blockIdx.x * 256 + threadIdx.x;  // < NTOK*DM
  int n = idx / DM, j = idx % DM;
  out[idx] = x2[idx]
           + wtok[2 * n] * pOut[(size_t)posOf[2 * n] * DM + j]
           + wtok[2 * n + 1] * pOut[(size_t)posOf[2 * n + 1] * DM + j];
}

// ---------------- launcher ----------------
extern "C" void kernel_launch(void* const* d_in, const int* in_sizes, int n_in,
                              void* d_out, int out_size, void* d_ws, size_t ws_size,
                              hipStream_t stream) {
  const float* x       = (const float*)d_in[0];
  const float* g_mamba = (const float*)d_in[1];
  const float* w_in    = (const float*)d_in[2];
  const float* conv_w  = (const float*)d_in[3];
  const float* conv_b  = (const float*)d_in[4];
  const float* w_xproj = (const float*)d_in[5];
  const float* w_dt    = (const float*)d_in[6];
  const float* b_dt    = (const float*)d_in[7];
  const float* A_log   = (const float*)d_in[8];
  const float* D_skip  = (const float*)d_in[9];
  const float* w_out   = (const float*)d_in[10];
  const float* g_moe   = (const float*)d_in[11];
  const float* w_router= (const float*)d_in[12];
  const float* g_exp   = (const float*)d_in[13];
  const float* w1      = (const float*)d_in[14];
  const float* w3      = (const float*)d_in[15];
  const float* w2      = (const float*)d_in[16];
  float* out = (float*)d_out;

  float* f = (float*)d_ws;
  size_t o = 0;
  float* hbuf = f + o;  o += (size_t)NTOK * DM;        // reused as rmsx AND Pbuf
  float* xz   = f + o;  o += (size_t)NTOK * 2 * DI;    // xz+xc+ybuf union == G
  float* xc   = f + o;  o += (size_t)NTOK * DI;        // (NPAIR*DFF floats exactly)
  float* ybuf = f + o;  o += (size_t)NTOK * DI;
  float* G    = xz;                                    // alias: 12,582,912 floats
  float* params = f + o; o += (size_t)NTOK * 33;
  float* x2   = f + o;  o += (size_t)NTOK * DM;        // also Sbuf during scan
  float* rmsx = hbuf;
  float* dtb  = f + o;                                 // NTOK*DI floats (== pOut region)
  float* pOut = f + o;  o += (size_t)NTOK * DI;        // == NPAIR*DM floats
  float* wtok = f + o;  o += NPAIR;
  float* wxpT = f + o;  o += (size_t)33 * DI;
  int* ib      = (int*)(f + o);
  int* counts  = ib;
  int* offsets = ib + 8;
  int* cursors = ib + 16;
  int* eidx    = ib + 24;
  int* posOf   = ib + 24 + NPAIR;
  int* pairTok = ib + 24 + 2 * NPAIR;

  // scan temporaries alias dead regions (CH*NSCAN*DS == NTOK*DM == 1.57M floats):
  //   Pbuf -> hbuf  (dead after gemm_in; rmsx written later by router)
  //   Sbuf -> x2    (written by gemm_out only after scanC)
  //   Hin  -> d_out (overwritten by k_combine at the end)
  float* Pbuf = hbuf;
  float* Sbuf = x2;
  float* Hin  = out;

  k_zero<<<1, 64, 0, stream>>>(ib, 24);
  k_rms1<<<NTOK, 256, 0, stream>>>(x, g_mamba, hbuf);
  k_gemm128<<<dim3((2 * DI) / 128, NTOK / 128), 256, 0, stream>>>(hbuf, w_in, nullptr, xz, NTOK, 2 * DI, DM);
  k_conv<<<(NTOK * DI) / 256, 256, 0, stream>>>(xz, conv_w, conv_b, xc);
  k_wxpT<<<(33 * DI + 255) / 256, 256, 0, stream>>>(w_xproj, wxpT);
  k_xproj2<<<NTOK, 256, 0, stream>>>(xc, wxpT, params);
  k_dt<<<(NTOK * DI) / 256, 256, 0, stream>>>(params, w_dt, b_dt, dtb);
  k_scanA<<<(CH * NSCAN * DS) / 256, 256, 0, stream>>>(params, dtb, xc, A_log, Pbuf, Sbuf);
  k_scanB<<<(NSCAN * DS) / 256, 256, 0, stream>>>(Pbuf, Sbuf, Hin);
  k_scanC<<<(CH * NSCAN * DS) / 256, 256, 0, stream>>>(params, dtb, xc, xz, A_log, D_skip, Hin, ybuf);
  k_gemm128<<<dim3(DM / 128, NTOK / 128), 256, 0, stream>>>(ybuf, w_out, x, x2, NTOK, DM, DI);
  k_router<<<NTOK, 256, 0, stream>>>(x2, g_moe, w_router, rmsx, eidx, wtok, counts);
  k_prefix<<<1, 1, 0, stream>>>(counts, offsets);
  k_scatter<<<8, 256, 0, stream>>>(eidx, offsets, cursors, pairTok, posOf);
  k_ffn1<<<dim3(DFF / 64, 16, NE), 256, 0, stream>>>(rmsx, g_exp, w1, w3, pairTok, offsets, counts, G);
  k_ffn2<<<dim3(DM / 128, 16, NE), 256, 0, stream>>>(G, w2, offsets, counts, pOut);
  k_combine<<<(NTOK * DM) / 256, 256, 0, stream>>>(x2, pOut, posOf, wtok, out);
}